// Round 4
// baseline (442.709 us; speedup 1.0000x reference)
//
#include <hip/hip_runtime.h>

#define BB 512
#define SS 1024
#define TT 48
#define GG 16          // batches per wave (MFMA N)

typedef __attribute__((ext_vector_type(8))) short short8;
typedef __attribute__((ext_vector_type(4))) float float4v;

// ---------- helpers ----------
__device__ __forceinline__ unsigned short f2bf(float x) {  // RNE f32->bf16
    unsigned u = __float_as_uint(x);
    u += 0x7FFFu + ((u >> 16) & 1u);
    return (unsigned short)(u >> 16);
}
// pack two f32 -> one uint: bf16(lo) | bf16(hi)<<16
__device__ __forceinline__ unsigned pk2bf(float lo, float hi) {
#if __has_builtin(__builtin_amdgcn_cvt_pk_bf16_f32)
    typedef __bf16 bf16x2 __attribute__((ext_vector_type(2)));
    union { bf16x2 v; unsigned u; } cv;
    cv.v = __builtin_amdgcn_cvt_pk_bf16_f32(lo, hi);
    return cv.u;
#else
    return __builtin_amdgcn_perm(__float_as_uint(hi) + 0x8000u,
                                 __float_as_uint(lo) + 0x8000u, 0x07060302u);
#endif
}
__device__ __forceinline__ float bflo(unsigned u) { return __uint_as_float(u << 16); }
__device__ __forceinline__ float bfhi(unsigned u) { return __uint_as_float(u & 0xFFFF0000u); }
__device__ __forceinline__ float wave_sum(float v) {
#pragma unroll
    for (int off = 32; off >= 1; off >>= 1) v += __shfl_xor(v, off, 64);
    return v;
}
__device__ __forceinline__ int wave_sum_i(int v) {
#pragma unroll
    for (int off = 32; off >= 1; off >>= 1) v += __shfl_xor(v, off, 64);
    return v;
}

// ---------- prep (merged): expE = mask ? exp(em) : 0 (bf16) + lengths + numerator ----------
__global__ __launch_bounds__(256)
void crf_prep(const float* __restrict__ em, const int* __restrict__ tags,
              const int* __restrict__ mask, const float* __restrict__ start_tr,
              const float* __restrict__ end_tr, const float* __restrict__ trans,
              uint2* __restrict__ expE, float* __restrict__ numer,
              int* __restrict__ lenArr) {
    const int b = blockIdx.x, tid = threadIdx.x;
    const float* emb = em + (size_t)b * SS * TT;
    const float4* src = (const float4*)emb;
    uint2* dst = expE + (size_t)b * (SS * TT / 4);
    const int* mk = mask + (size_t)b * SS;
    const int* tg = tags + (size_t)b * SS;

    for (int i = tid; i < SS * TT / 4; i += 256) {
        int t = i / (TT / 4);
        float4 v = src[i];
        uint2 o;
        o.x = pk2bf(__expf(v.x), __expf(v.y));
        o.y = pk2bf(__expf(v.z), __expf(v.w));
        if (!mk[t]) { o.x = 0u; o.y = 0u; }   // rows >= len forced to zero
        dst[i] = o;
    }
    // lengths + gold-path score
    int cnt = 0; float ns = 0.f;
    for (int s = tid; s < SS; s += 256) {
        int m = mk[s];
        cnt += (m != 0);
        if (s >= 1 && m) {
            int tp = tg[s - 1], tc = tg[s];
            ns += trans[tp * TT + tc] + emb[s * TT + tc];
        }
    }
    float wsum = wave_sum(ns);
    int wcnt = wave_sum_i(cnt);
    __shared__ float sf[4]; __shared__ int si[4];
    if ((tid & 63) == 0) { sf[tid >> 6] = wsum; si[tid >> 6] = wcnt; }
    __syncthreads();
    if (tid == 0) {
        float tot = sf[0] + sf[1] + sf[2] + sf[3];
        int L = si[0] + si[1] + si[2] + si[3];
        int t0 = tg[0];
        tot += start_tr[t0] + emb[t0] + end_tr[tg[L - 1]];
        numer[b] = tot;
        lenArr[b] = L;
    }
}

// ---------- main recurrence: 1 wave = 16 batches, 6 MFMA/step ----------
// State s = 16a + 4q + r -> C tile a, quad q, reg r (col = lane&15 = batch).
// k-slot map: states 0..31 -> B frag0 (j = 4a + r), states 32..47 -> frag1 (j = r).
// Register ring: 24 NAMED uint2 (no arrays -> no scratch), single pointer +768/iter,
// all loads immediate-offset. Rows >= len are zero => dead batches freeze p = 0.
__global__ __launch_bounds__(64)
void crf_fwd(const uint2* __restrict__ expE, const float* __restrict__ start_tr,
             const float* __restrict__ end_tr, const float* __restrict__ trans,
             const int* __restrict__ lenArr, float* __restrict__ denomArr) {
    const int lane = threadIdx.x & 63;
    const int n = lane & 15, q = lane >> 4;
    const int bb = blockIdx.x * GG + n;

    // A[m = s_out][k-slot(s_in)] = exp(trans[s_out][s_in])
    short8 afr[3][2];
#pragma unroll
    for (int mt = 0; mt < 3; ++mt) {
        const int so = mt * 16 + n;
#pragma unroll
        for (int kt = 0; kt < 2; ++kt) {
            short8 a;
#pragma unroll
            for (int i = 0; i < 8; ++i) {
                int si_;
                if (kt == 0) si_ = (i < 4) ? (q * 4 + i) : (16 + q * 4 + (i - 4));
                else         si_ = (i < 4) ? (32 + q * 4 + i) : -1;
                a[i] = (si_ >= 0) ? (short)f2bf(__expf(trans[so * TT + si_])) : (short)0;
            }
            afr[mt][kt] = a;
        }
    }

    const char* eptr = (const char*)expE + (size_t)bb * (SS * TT * 2) + (size_t)q * 8;

    // init: p = exp(start) * e_row0
    float p[3][4];
#pragma unroll
    for (int mt = 0; mt < 3; ++mt) {
        uint2 e = *(const uint2*)(eptr + mt * 32);
        float e0 = bflo(e.x), e1 = bfhi(e.x), e2 = bflo(e.y), e3 = bfhi(e.y);
        int sb = mt * 16 + q * 4;
        p[mt][0] = __expf(start_tr[sb + 0]) * e0;
        p[mt][1] = __expf(start_tr[sb + 1]) * e1;
        p[mt][2] = __expf(start_tr[sb + 2]) * e2;
        p[mt][3] = __expf(start_tr[sb + 3]) * e3;
    }
    eptr += 96;  // -> row 1

    const int len = lenArr[bb];
    int Lmax = len;
#pragma unroll
    for (int off = 1; off < 64; off <<= 1) {
        int o = __shfl_xor(Lmax, off, 64);
        Lmax = Lmax > o ? Lmax : o;
    }

    // capture latches
    bool cc0 = (len == 1);
    float dc[3][4];
#pragma unroll
    for (int mt = 0; mt < 3; ++mt)
#pragma unroll
        for (int r = 0; r < 4; ++r) dc[mt][r] = cc0 ? p[mt][r] : 0.f;
    float lcap = 0.f, logscale = 0.f;

    // NAMED register ring (24 x uint2)
    uint2 s0a, s0b, s0c, s1a, s1b, s1c, s2a, s2b, s2c, s3a, s3b, s3c;
    uint2 s4a, s4b, s4c, s5a, s5b, s5c, s6a, s6b, s6c, s7a, s7b, s7c;

#define LD3(u, RA, RB, RC, EX)                                   \
    RA = *(const uint2*)(eptr + (u) * 96 + (EX) + 0);            \
    RB = *(const uint2*)(eptr + (u) * 96 + (EX) + 32);           \
    RC = *(const uint2*)(eptr + (u) * 96 + (EX) + 64);

    LD3(0, s0a, s0b, s0c, 0) LD3(1, s1a, s1b, s1c, 0)
    LD3(2, s2a, s2b, s2c, 0) LD3(3, s3a, s3b, s3c, 0)
    LD3(4, s4a, s4b, s4c, 0) LD3(5, s5a, s5b, s5c, 0)
    LD3(6, s6a, s6b, s6c, 0) LD3(7, s7a, s7b, s7c, 0)

    const float4v Z = {0.f, 0.f, 0.f, 0.f};

#define STEP(u, RA, RB, RC) {                                                          \
    union { short8 v; unsigned w[4]; } B0, B1;                                         \
    B0.w[0] = pk2bf(p[0][0], p[0][1]); B0.w[1] = pk2bf(p[0][2], p[0][3]);              \
    B0.w[2] = pk2bf(p[1][0], p[1][1]); B0.w[3] = pk2bf(p[1][2], p[1][3]);              \
    B1.w[0] = pk2bf(p[2][0], p[2][1]); B1.w[1] = pk2bf(p[2][2], p[2][3]);              \
    B1.w[2] = 0u; B1.w[3] = 0u;                                                        \
    float4v A0 = __builtin_amdgcn_mfma_f32_16x16x32_bf16(afr[0][0], B0.v, Z, 0, 0, 0); \
    float4v A1 = __builtin_amdgcn_mfma_f32_16x16x32_bf16(afr[1][0], B0.v, Z, 0, 0, 0); \
    float4v A2 = __builtin_amdgcn_mfma_f32_16x16x32_bf16(afr[2][0], B0.v, Z, 0, 0, 0); \
    A0 = __builtin_amdgcn_mfma_f32_16x16x32_bf16(afr[0][1], B1.v, A0, 0, 0, 0);        \
    A1 = __builtin_amdgcn_mfma_f32_16x16x32_bf16(afr[1][1], B1.v, A1, 0, 0, 0);        \
    A2 = __builtin_amdgcn_mfma_f32_16x16x32_bf16(afr[2][1], B1.v, A2, 0, 0, 0);        \
    p[0][0] = A0[0] * bflo(RA.x); p[0][1] = A0[1] * bfhi(RA.x);                        \
    p[0][2] = A0[2] * bflo(RA.y); p[0][3] = A0[3] * bfhi(RA.y);                        \
    p[1][0] = A1[0] * bflo(RB.x); p[1][1] = A1[1] * bfhi(RB.x);                        \
    p[1][2] = A1[2] * bflo(RB.y); p[1][3] = A1[3] * bfhi(RB.y);                        \
    p[2][0] = A2[0] * bflo(RC.x); p[2][1] = A2[1] * bfhi(RC.x);                        \
    p[2][2] = A2[2] * bflo(RC.y); p[2][3] = A2[3] * bfhi(RC.y);                        \
    LD3(u, RA, RB, RC, 768)                                                            \
    bool cc = (len == tb + (u) + 1);                                                   \
    dc[0][0] = cc ? p[0][0] : dc[0][0]; dc[0][1] = cc ? p[0][1] : dc[0][1];            \
    dc[0][2] = cc ? p[0][2] : dc[0][2]; dc[0][3] = cc ? p[0][3] : dc[0][3];            \
    dc[1][0] = cc ? p[1][0] : dc[1][0]; dc[1][1] = cc ? p[1][1] : dc[1][1];            \
    dc[1][2] = cc ? p[1][2] : dc[1][2]; dc[1][3] = cc ? p[1][3] : dc[1][3];            \
    dc[2][0] = cc ? p[2][0] : dc[2][0]; dc[2][1] = cc ? p[2][1] : dc[2][1];            \
    dc[2][2] = cc ? p[2][2] : dc[2][2]; dc[2][3] = cc ? p[2][3] : dc[2][3];            \
    lcap = cc ? logscale : lcap; }

    for (int tb = 1; tb < Lmax; tb += 8) {
        STEP(0, s0a, s0b, s0c)
        STEP(1, s1a, s1b, s1c)
        STEP(2, s2a, s2b, s2c)
        STEP(3, s3a, s3b, s3c)
        STEP(4, s4a, s4b, s4c)
        STEP(5, s5a, s5b, s5c)
        STEP(6, s6a, s6b, s6c)
        STEP(7, s7a, s7b, s7c)
        {   // renorm every 8 steps
            float m = fmaxf(p[0][0], p[0][1]);
            m = fmaxf(m, fmaxf(p[0][2], p[0][3]));
            m = fmaxf(m, fmaxf(p[1][0], p[1][1]));
            m = fmaxf(m, fmaxf(p[1][2], p[1][3]));
            m = fmaxf(m, fmaxf(p[2][0], p[2][1]));
            m = fmaxf(m, fmaxf(p[2][2], p[2][3]));
            m = fmaxf(m, __shfl_xor(m, 16, 64));
            m = fmaxf(m, __shfl_xor(m, 32, 64));
            m = fmaxf(m, 1e-30f);
            logscale += __logf(m);
            float rm = __builtin_amdgcn_rcpf(m);
            p[0][0] *= rm; p[0][1] *= rm; p[0][2] *= rm; p[0][3] *= rm;
            p[1][0] *= rm; p[1][1] *= rm; p[1][2] *= rm; p[1][3] *= rm;
            p[2][0] *= rm; p[2][1] *= rm; p[2][2] *= rm; p[2][3] *= rm;
        }
        eptr += 768;
    }

    // epilogue: denom = lcap + log( sum_s dc[s] * exp(end[s]) )
    float pe = 0.f;
#pragma unroll
    for (int mt = 0; mt < 3; ++mt) {
        int sb = mt * 16 + q * 4;
        pe = fmaf(dc[mt][0], __expf(end_tr[sb + 0]), pe);
        pe = fmaf(dc[mt][1], __expf(end_tr[sb + 1]), pe);
        pe = fmaf(dc[mt][2], __expf(end_tr[sb + 2]), pe);
        pe = fmaf(dc[mt][3], __expf(end_tr[sb + 3]), pe);
    }
    pe += __shfl_xor(pe, 16, 64);
    pe += __shfl_xor(pe, 32, 64);
    if (lane < 16) denomArr[bb] = lcap + __logf(pe);
}

__global__ __launch_bounds__(64)
void crf_reduce(const float* __restrict__ denom, const float* __restrict__ numer,
                float* __restrict__ out) {
    int lane = threadIdx.x;
    float s = 0.f;
    for (int i = lane; i < BB; i += 64) s += denom[i] - numer[i];
    s = wave_sum(s);
    if (lane == 0) out[0] = s * (1.0f / (float)BB);
}

extern "C" void kernel_launch(void* const* d_in, const int* in_sizes, int n_in,
                              void* d_out, int out_size, void* d_ws, size_t ws_size,
                              hipStream_t stream) {
    const float* emissions = (const float*)d_in[0];
    const int*   tags      = (const int*)d_in[1];
    const int*   mask      = (const int*)d_in[2];
    const float* start_tr  = (const float*)d_in[3];
    const float* end_tr    = (const float*)d_in[4];
    const float* trans     = (const float*)d_in[5];

    // Layout: expE FIRST so fwd's bounded over-read (<=1.5 KB past the last
    // batch's rows) lands in the scalar tail region, still inside ws.
    char* ws = (char*)d_ws;
    const size_t EXPE_BYTES = (size_t)BB * SS * TT * 2;   // 50,331,648
    uint2* expE  = (uint2*)ws;
    float* denom = (float*)(ws + EXPE_BYTES + 2048);      // 512 f32
    float* numer = (float*)(ws + EXPE_BYTES + 4096);      // 512 f32
    int*   lenA  = (int*)(ws + EXPE_BYTES + 6144);        // 512 i32
    // total need = EXPE_BYTES + 8192, identical to rounds 2-3 (known to fit)

    crf_prep<<<BB, 256, 0, stream>>>(emissions, tags, mask, start_tr, end_tr,
                                     trans, expE, numer, lenA);
    crf_fwd<<<BB / GG, 64, 0, stream>>>(expE, start_tr, end_tr, trans, lenA, denom);
    crf_reduce<<<1, 64, 0, stream>>>(denom, numer, (float*)d_out);
}

// Round 5
// 322.138 us; speedup vs baseline: 1.3743x; 1.3743x over previous
//
#include <hip/hip_runtime.h>

#define BB 512
#define SS 1024
#define TT 48
#define GG 16          // batches per WG (MFMA N)
#define CK 8           // rows per chunk
#define NSLOT 5        // LDS ring slots

typedef __attribute__((ext_vector_type(8))) short short8;
typedef __attribute__((ext_vector_type(4))) float float4v;

// ---------- helpers ----------
__device__ __forceinline__ unsigned short f2bf(float x) {
    unsigned u = __float_as_uint(x);
    u += 0x7FFFu + ((u >> 16) & 1u);
    return (unsigned short)(u >> 16);
}
__device__ __forceinline__ unsigned pk2bf(float lo, float hi) {
#if __has_builtin(__builtin_amdgcn_cvt_pk_bf16_f32)
    typedef __bf16 bf16x2 __attribute__((ext_vector_type(2)));
    union { bf16x2 v; unsigned u; } cv;
    cv.v = __builtin_amdgcn_cvt_pk_bf16_f32(lo, hi);
    return cv.u;
#else
    return __builtin_amdgcn_perm(__float_as_uint(hi) + 0x8000u,
                                 __float_as_uint(lo) + 0x8000u, 0x07060302u);
#endif
}
__device__ __forceinline__ float bflo(unsigned u) { return __uint_as_float(u << 16); }
__device__ __forceinline__ float bfhi(unsigned u) { return __uint_as_float(u & 0xFFFF0000u); }
__device__ __forceinline__ float wave_sum(float v) {
#pragma unroll
    for (int off = 32; off >= 1; off >>= 1) v += __shfl_xor(v, off, 64);
    return v;
}
__device__ __forceinline__ int wave_sum_i(int v) {
#pragma unroll
    for (int off = 32; off >= 1; off >>= 1) v += __shfl_xor(v, off, 64);
    return v;
}

// ---------- prep: lengths + gold-path numerator only (no expE pass) ----------
__global__ __launch_bounds__(256)
void crf_numer(const float* __restrict__ em, const int* __restrict__ tags,
               const int* __restrict__ mask, const float* __restrict__ start_tr,
               const float* __restrict__ end_tr, const float* __restrict__ trans,
               float* __restrict__ numer, int* __restrict__ lenArr) {
    const int b = blockIdx.x, tid = threadIdx.x;
    const float* emb = em + (size_t)b * SS * TT;
    const int* tg = tags + (size_t)b * SS;
    const int* mk = mask + (size_t)b * SS;
    int cnt = 0; float ns = 0.f;
    for (int s = tid; s < SS; s += 256) {
        int m = mk[s];
        cnt += (m != 0);
        if (s >= 1 && m) {
            int tp = tg[s - 1], tc = tg[s];
            ns += trans[tp * TT + tc] + emb[s * TT + tc];
        }
    }
    float wsum = wave_sum(ns);
    int wcnt = wave_sum_i(cnt);
    __shared__ float sf[4]; __shared__ int si[4];
    if ((tid & 63) == 0) { sf[tid >> 6] = wsum; si[tid >> 6] = wcnt; }
    __syncthreads();
    if (tid == 0) {
        float tot = sf[0] + sf[1] + sf[2] + sf[3];
        int L = si[0] + si[1] + si[2] + si[3];
        int t0 = tg[0];
        tot += start_tr[t0] + emb[t0] + end_tr[tg[L - 1]];
        numer[b] = tot;
        lenArr[b] = L;
    }
}

// ---------- main: 4 waves/WG. wave0 = MFMA consumer; waves1-3 = exp producers ----------
// LDS ring entry (slot, row u, section j, entry e) holds bf16x2 pair:
//   states {j*16+q*4+0..3} of batch n, e = n*4+q. Producer lane == e directly.
// Consumer lane (n=lane&15, q=lane>>4) reads entry (n*4+q), section mt.
__global__ __launch_bounds__(256)
void crf_fwd(const float* __restrict__ em, const float* __restrict__ start_tr,
             const float* __restrict__ end_tr, const float* __restrict__ trans,
             const int* __restrict__ lenArr, float* __restrict__ denomArr) {
    __shared__ uint2 ring[NSLOT * CK * 3 * 64];   // 61440 B

    const int tid = threadIdx.x;
    const int wave = tid >> 6, lane = tid & 63;
    const int wgbase = blockIdx.x * GG;

    if (wave == 0) {
        // ================= CONSUMER =================
        const int n = lane & 15, q = lane >> 4;
        const int bb = wgbase + n;
        const int ec = n * 4 + q;

        // A[m=s_out][k-slot(s_in)] = exp(trans[s_out][s_in])
        short8 afr[3][2];
#pragma unroll
        for (int mt = 0; mt < 3; ++mt) {
            const int so = mt * 16 + n;
#pragma unroll
            for (int kt = 0; kt < 2; ++kt) {
                short8 a;
#pragma unroll
                for (int i = 0; i < 8; ++i) {
                    int si_;
                    if (kt == 0) si_ = (i < 4) ? (q * 4 + i) : (16 + q * 4 + (i - 4));
                    else         si_ = (i < 4) ? (32 + q * 4 + i) : -1;
                    a[i] = (si_ >= 0) ? (short)f2bf(__expf(trans[so * TT + si_])) : (short)0;
                }
                afr[mt][kt] = a;
            }
        }

        // init p = exp(start) * exp(em row0)
        const float* em0 = em + (size_t)bb * SS * TT + q * 4;
        float p[3][4];
#pragma unroll
        for (int mt = 0; mt < 3; ++mt) {
            float4 v = *(const float4*)(em0 + mt * 16);
            int sb = mt * 16 + q * 4;
            p[mt][0] = __expf(start_tr[sb + 0] + v.x);
            p[mt][1] = __expf(start_tr[sb + 1] + v.y);
            p[mt][2] = __expf(start_tr[sb + 2] + v.z);
            p[mt][3] = __expf(start_tr[sb + 3] + v.w);
        }

        const int len = lenArr[bb];
        int Lmax = len;
#pragma unroll
        for (int off = 1; off < 64; off <<= 1) {
            int o = __shfl_xor(Lmax, off, 64);
            Lmax = Lmax > o ? Lmax : o;
        }
        const int P = (Lmax + 6) >> 3;   // ceil((Lmax-1)/8)

        bool cc0 = (len == 1);
        float dc[3][4];
#pragma unroll
        for (int mt = 0; mt < 3; ++mt)
#pragma unroll
            for (int r = 0; r < 4; ++r) dc[mt][r] = cc0 ? p[mt][r] : 0.f;
        float lcap = 0.f, logscale = 0.f;
        const float4v Z = {0.f, 0.f, 0.f, 0.f};

        for (int pp = -3; pp < P; ++pp) {
            if (pp >= 0) {
                const uint2* rp = &ring[(pp % NSLOT) * (CK * 3 * 64) + ec];
                uint2 c0 = rp[0], c1 = rp[64], c2v = rp[128];
#pragma unroll
                for (int u = 0; u < 8; ++u) {
                    uint2 n0, n1, n2;
                    if (u < 7) {
                        n0 = rp[(u + 1) * 192];
                        n1 = rp[(u + 1) * 192 + 64];
                        n2 = rp[(u + 1) * 192 + 128];
                    }
                    // pack p -> B frags
                    union { short8 v; unsigned w[4]; } B0, B1;
                    B0.w[0] = pk2bf(p[0][0], p[0][1]); B0.w[1] = pk2bf(p[0][2], p[0][3]);
                    B0.w[2] = pk2bf(p[1][0], p[1][1]); B0.w[3] = pk2bf(p[1][2], p[1][3]);
                    B1.w[0] = pk2bf(p[2][0], p[2][1]); B1.w[1] = pk2bf(p[2][2], p[2][3]);
                    B1.w[2] = 0u; B1.w[3] = 0u;
                    float4v A0 = __builtin_amdgcn_mfma_f32_16x16x32_bf16(afr[0][0], B0.v, Z, 0, 0, 0);
                    float4v A1 = __builtin_amdgcn_mfma_f32_16x16x32_bf16(afr[1][0], B0.v, Z, 0, 0, 0);
                    float4v A2 = __builtin_amdgcn_mfma_f32_16x16x32_bf16(afr[2][0], B0.v, Z, 0, 0, 0);
                    A0 = __builtin_amdgcn_mfma_f32_16x16x32_bf16(afr[0][1], B1.v, A0, 0, 0, 0);
                    A1 = __builtin_amdgcn_mfma_f32_16x16x32_bf16(afr[1][1], B1.v, A1, 0, 0, 0);
                    A2 = __builtin_amdgcn_mfma_f32_16x16x32_bf16(afr[2][1], B1.v, A2, 0, 0, 0);
                    p[0][0] = A0[0] * bflo(c0.x); p[0][1] = A0[1] * bfhi(c0.x);
                    p[0][2] = A0[2] * bflo(c0.y); p[0][3] = A0[3] * bfhi(c0.y);
                    p[1][0] = A1[0] * bflo(c1.x); p[1][1] = A1[1] * bfhi(c1.x);
                    p[1][2] = A1[2] * bflo(c1.y); p[1][3] = A1[3] * bfhi(c1.y);
                    p[2][0] = A2[0] * bflo(c2v.x); p[2][1] = A2[1] * bfhi(c2v.x);
                    p[2][2] = A2[2] * bflo(c2v.y); p[2][3] = A2[3] * bfhi(c2v.y);
                    // latch at t == len-1   (t = 1 + 8*pp + u)
                    bool cc = (len == 8 * pp + u + 2);
#pragma unroll
                    for (int mt = 0; mt < 3; ++mt)
#pragma unroll
                        for (int r = 0; r < 4; ++r) dc[mt][r] = cc ? p[mt][r] : dc[mt][r];
                    lcap = cc ? logscale : lcap;
                    c0 = n0; c1 = n1; c2v = n2;
                    if (u == 7) {   // renorm once per chunk
                        float m = fmaxf(p[0][0], p[0][1]);
                        m = fmaxf(m, fmaxf(p[0][2], p[0][3]));
                        m = fmaxf(m, fmaxf(p[1][0], p[1][1]));
                        m = fmaxf(m, fmaxf(p[1][2], p[1][3]));
                        m = fmaxf(m, fmaxf(p[2][0], p[2][1]));
                        m = fmaxf(m, fmaxf(p[2][2], p[2][3]));
                        m = fmaxf(m, __shfl_xor(m, 16, 64));
                        m = fmaxf(m, __shfl_xor(m, 32, 64));
                        m = fmaxf(m, 1e-30f);
                        logscale += __logf(m);
                        float rm = __builtin_amdgcn_rcpf(m);
#pragma unroll
                        for (int mt = 0; mt < 3; ++mt)
#pragma unroll
                            for (int r = 0; r < 4; ++r) p[mt][r] *= rm;
                    }
                }
            }
            __builtin_amdgcn_s_barrier();
        }

        // epilogue
        float pe = 0.f;
#pragma unroll
        for (int mt = 0; mt < 3; ++mt) {
            int sb = mt * 16 + q * 4;
            pe = fmaf(dc[mt][0], __expf(end_tr[sb + 0]), pe);
            pe = fmaf(dc[mt][1], __expf(end_tr[sb + 1]), pe);
            pe = fmaf(dc[mt][2], __expf(end_tr[sb + 2]), pe);
            pe = fmaf(dc[mt][3], __expf(end_tr[sb + 3]), pe);
        }
        pe += __shfl_xor(pe, 16, 64);
        pe += __shfl_xor(pe, 32, 64);
        if (lane < 16) denomArr[bb] = lcap + __logf(pe);

    } else {
        // ================= PRODUCERS (waves 1..3) =================
        const int my = wave - 1;               // handles chunks c ≡ my (mod 3)
        const int nb = lane >> 2, q4 = lane & 3;
        const int bb = wgbase + nb;
        const int len_v = lenArr[bb];
        int Lmax = len_v;
#pragma unroll
        for (int off = 1; off < 64; off <<= 1) {
            int o = __shfl_xor(Lmax, off, 64);
            Lmax = Lmax > o ? Lmax : o;
        }
        const int P = (Lmax + 6) >> 3;

        const float* emP = em + (size_t)bb * SS * TT + q4 * 4;
        float4 buf[CK][3];

        for (int pp = -3; pp < P; ++pp) {
            int c1 = pp + 3;                    // issue loads for chunk c1
            if (c1 < P && (c1 % 3) == my) {
                if (8 * c1 + 8 <= SS - 1) {
                    const float* cb = emP + (size_t)(1 + 8 * c1) * TT;
#pragma unroll
                    for (int u = 0; u < CK; ++u)
#pragma unroll
                        for (int j = 0; j < 3; ++j)
                            buf[u][j] = *(const float4*)(cb + u * TT + j * 16);
                } else {
#pragma unroll
                    for (int u = 0; u < CK; ++u) {
                        int t = 1 + 8 * c1 + u; t = t < SS ? t : SS - 1;
#pragma unroll
                        for (int j = 0; j < 3; ++j)
                            buf[u][j] = *(const float4*)(emP + (size_t)t * TT + j * 16);
                    }
                }
            }
            int c2 = pp + 1;                    // process + commit chunk c2
            if (c2 >= 0 && c2 < P && (c2 % 3) == my) {
                uint2* wp = &ring[(c2 % NSLOT) * (CK * 3 * 64) + lane];
#pragma unroll
                for (int u = 0; u < CK; ++u) {
                    int t = 1 + 8 * c2 + u;
                    bool live = t < len_v;
#pragma unroll
                    for (int j = 0; j < 3; ++j) {
                        float4 v = buf[u][j];
                        unsigned lox = pk2bf(__expf(v.x), __expf(v.y));
                        unsigned hix = pk2bf(__expf(v.z), __expf(v.w));
                        uint2 o;
                        o.x = live ? lox : 0u;
                        o.y = live ? hix : 0u;
                        wp[u * 192 + j * 64] = o;
                    }
                }
            }
            __builtin_amdgcn_s_waitcnt(0xC07F);  // lgkmcnt(0) only — vmcnt untouched
            __builtin_amdgcn_s_barrier();
        }
    }
}

__global__ __launch_bounds__(64)
void crf_reduce(const float* __restrict__ denom, const float* __restrict__ numer,
                float* __restrict__ out) {
    int lane = threadIdx.x;
    float s = 0.f;
    for (int i = lane; i < BB; i += 64) s += denom[i] - numer[i];
    s = wave_sum(s);
    if (lane == 0) out[0] = s * (1.0f / (float)BB);
}

extern "C" void kernel_launch(void* const* d_in, const int* in_sizes, int n_in,
                              void* d_out, int out_size, void* d_ws, size_t ws_size,
                              hipStream_t stream) {
    const float* emissions = (const float*)d_in[0];
    const int*   tags      = (const int*)d_in[1];
    const int*   mask      = (const int*)d_in[2];
    const float* start_tr  = (const float*)d_in[3];
    const float* end_tr    = (const float*)d_in[4];
    const float* trans     = (const float*)d_in[5];

    char* ws = (char*)d_ws;
    float* denom = (float*)ws;               // 512 f32
    float* numer = (float*)(ws + 2048);      // 512 f32
    int*   lenA  = (int*)(ws + 4096);        // 512 i32

    crf_numer<<<BB, 256, 0, stream>>>(emissions, tags, mask, start_tr, end_tr,
                                      trans, numer, lenA);
    crf_fwd<<<BB / GG, 256, 0, stream>>>(emissions, start_tr, end_tr, trans,
                                         lenA, denom);
    crf_reduce<<<1, 64, 0, stream>>>(denom, numer, (float*)d_out);
}

// Round 6
// 321.574 us; speedup vs baseline: 1.3767x; 1.0018x over previous
//
#include <hip/hip_runtime.h>

#define BB 512
#define SS 1024
#define TT 48
#define GG 16          // batches per WG (MFMA N)
#define CK 8           // rows per chunk
#define NSLOT 5        // LDS ring slots

typedef __attribute__((ext_vector_type(8))) short short8;
typedef __attribute__((ext_vector_type(4))) float float4v;

// ---------- helpers ----------
__device__ __forceinline__ unsigned short f2bf(float x) {
    unsigned u = __float_as_uint(x);
    u += 0x7FFFu + ((u >> 16) & 1u);
    return (unsigned short)(u >> 16);
}
__device__ __forceinline__ unsigned pk2bf(float lo, float hi) {
#if __has_builtin(__builtin_amdgcn_cvt_pk_bf16_f32)
    typedef __bf16 bf16x2 __attribute__((ext_vector_type(2)));
    union { bf16x2 v; unsigned u; } cv;
    cv.v = __builtin_amdgcn_cvt_pk_bf16_f32(lo, hi);
    return cv.u;
#else
    return __builtin_amdgcn_perm(__float_as_uint(hi) + 0x8000u,
                                 __float_as_uint(lo) + 0x8000u, 0x07060302u);
#endif
}
__device__ __forceinline__ float bflo(unsigned u) { return __uint_as_float(u << 16); }
__device__ __forceinline__ float bfhi(unsigned u) { return __uint_as_float(u & 0xFFFF0000u); }
__device__ __forceinline__ float wave_sum(float v) {
#pragma unroll
    for (int off = 32; off >= 1; off >>= 1) v += __shfl_xor(v, off, 64);
    return v;
}
__device__ __forceinline__ int wave_sum_i(int v) {
#pragma unroll
    for (int off = 32; off >= 1; off >>= 1) v += __shfl_xor(v, off, 64);
    return v;
}

// ---------- prep: lengths + gold-path numerator ----------
__global__ __launch_bounds__(256)
void crf_numer(const float* __restrict__ em, const int* __restrict__ tags,
               const int* __restrict__ mask, const float* __restrict__ start_tr,
               const float* __restrict__ end_tr, const float* __restrict__ trans,
               float* __restrict__ numer, int* __restrict__ lenArr) {
    const int b = blockIdx.x, tid = threadIdx.x;
    const float* emb = em + (size_t)b * SS * TT;
    const int* tg = tags + (size_t)b * SS;
    const int* mk = mask + (size_t)b * SS;
    int cnt = 0; float ns = 0.f;
    for (int s = tid; s < SS; s += 256) {
        int m = mk[s];
        cnt += (m != 0);
        if (s >= 1 && m) {
            int tp = tg[s - 1], tc = tg[s];
            ns += trans[tp * TT + tc] + emb[s * TT + tc];
        }
    }
    float wsum = wave_sum(ns);
    int wcnt = wave_sum_i(cnt);
    __shared__ float sf[4]; __shared__ int si[4];
    if ((tid & 63) == 0) { sf[tid >> 6] = wsum; si[tid >> 6] = wcnt; }
    __syncthreads();
    if (tid == 0) {
        float tot = sf[0] + sf[1] + sf[2] + sf[3];
        int L = si[0] + si[1] + si[2] + si[3];
        int t0 = tg[0];
        tot += start_tr[t0] + emb[t0] + end_tr[tg[L - 1]];
        numer[b] = tot;
        lenArr[b] = L;
    }
}

// ---------- main: 5 waves/WG. wave0 = MFMA consumer; waves1-4 = 2 producer teams ----------
// LDS ring entry (slot, row u, section j, entry e): e == consumer lane (q*16+n),
// bf16x2 pair = states {j*16+q*4 .. +3} of batch n. Producers use the SAME lane
// mapping (nb=lane&15, q4=lane>>4) so both read & write at entry==lane: conflict-free.
__global__ __launch_bounds__(320, 1)
void crf_fwd(const float* __restrict__ em, const float* __restrict__ start_tr,
             const float* __restrict__ end_tr, const float* __restrict__ trans,
             const int* __restrict__ lenArr, float* __restrict__ denomArr) {
    __shared__ uint2 ring[NSLOT * CK * 3 * 64];   // 61440 B

    const int tid = threadIdx.x;
    const int wave = tid >> 6, lane = tid & 63;
    const int wgbase = blockIdx.x * GG;

    if (wave == 0) {
        // ================= CONSUMER =================
        const int n = lane & 15, q = lane >> 4;
        const int bb = wgbase + n;

        // A[m=s_out][k-slot(s_in)] = exp(trans[s_out][s_in])
        short8 afr[3][2];
#pragma unroll
        for (int mt = 0; mt < 3; ++mt) {
            const int so = mt * 16 + n;
#pragma unroll
            for (int kt = 0; kt < 2; ++kt) {
                short8 a;
#pragma unroll
                for (int i = 0; i < 8; ++i) {
                    int si_;
                    if (kt == 0) si_ = (i < 4) ? (q * 4 + i) : (16 + q * 4 + (i - 4));
                    else         si_ = (i < 4) ? (32 + q * 4 + i) : -1;
                    a[i] = (si_ >= 0) ? (short)f2bf(__expf(trans[so * TT + si_])) : (short)0;
                }
                afr[mt][kt] = a;
            }
        }

        // init p = exp(start) * exp(em row0)
        const float* em0 = em + (size_t)bb * SS * TT + q * 4;
        float p[3][4];
#pragma unroll
        for (int mt = 0; mt < 3; ++mt) {
            float4 v = *(const float4*)(em0 + mt * 16);
            int sb = mt * 16 + q * 4;
            p[mt][0] = __expf(start_tr[sb + 0] + v.x);
            p[mt][1] = __expf(start_tr[sb + 1] + v.y);
            p[mt][2] = __expf(start_tr[sb + 2] + v.z);
            p[mt][3] = __expf(start_tr[sb + 3] + v.w);
        }

        const int len = lenArr[bb];
        int Lmax = len;
#pragma unroll
        for (int off = 1; off < 64; off <<= 1) {
            int o = __shfl_xor(Lmax, off, 64);
            Lmax = Lmax > o ? Lmax : o;
        }
        const int P = (Lmax + 6) >> 3;   // ceil((Lmax-1)/8)

        bool cc0 = (len == 1);
        float dc[3][4];
#pragma unroll
        for (int mt = 0; mt < 3; ++mt)
#pragma unroll
            for (int r = 0; r < 4; ++r) dc[mt][r] = cc0 ? p[mt][r] : 0.f;
        float lcap = 0.f, logscale = 0.f;
        const float4v Z = {0.f, 0.f, 0.f, 0.f};

        for (int pp = -3; pp < P; ++pp) {
            if (pp >= 0) {
                const uint2* rp = &ring[(pp % NSLOT) * (CK * 3 * 64) + lane];
                uint2 c0 = rp[0], c1 = rp[64], c2v = rp[128];
#pragma unroll
                for (int u = 0; u < 8; ++u) {
                    uint2 n0, n1, n2;
                    if (u < 7) {
                        n0 = rp[(u + 1) * 192];
                        n1 = rp[(u + 1) * 192 + 64];
                        n2 = rp[(u + 1) * 192 + 128];
                    }
                    union { short8 v; unsigned w[4]; } B0, B1;
                    B0.w[0] = pk2bf(p[0][0], p[0][1]); B0.w[1] = pk2bf(p[0][2], p[0][3]);
                    B0.w[2] = pk2bf(p[1][0], p[1][1]); B0.w[3] = pk2bf(p[1][2], p[1][3]);
                    B1.w[0] = pk2bf(p[2][0], p[2][1]); B1.w[1] = pk2bf(p[2][2], p[2][3]);
                    B1.w[2] = 0u; B1.w[3] = 0u;
                    float4v A0 = __builtin_amdgcn_mfma_f32_16x16x32_bf16(afr[0][0], B0.v, Z, 0, 0, 0);
                    float4v A1 = __builtin_amdgcn_mfma_f32_16x16x32_bf16(afr[1][0], B0.v, Z, 0, 0, 0);
                    float4v A2 = __builtin_amdgcn_mfma_f32_16x16x32_bf16(afr[2][0], B0.v, Z, 0, 0, 0);
                    A0 = __builtin_amdgcn_mfma_f32_16x16x32_bf16(afr[0][1], B1.v, A0, 0, 0, 0);
                    A1 = __builtin_amdgcn_mfma_f32_16x16x32_bf16(afr[1][1], B1.v, A1, 0, 0, 0);
                    A2 = __builtin_amdgcn_mfma_f32_16x16x32_bf16(afr[2][1], B1.v, A2, 0, 0, 0);
                    p[0][0] = A0[0] * bflo(c0.x); p[0][1] = A0[1] * bfhi(c0.x);
                    p[0][2] = A0[2] * bflo(c0.y); p[0][3] = A0[3] * bfhi(c0.y);
                    p[1][0] = A1[0] * bflo(c1.x); p[1][1] = A1[1] * bfhi(c1.x);
                    p[1][2] = A1[2] * bflo(c1.y); p[1][3] = A1[3] * bfhi(c1.y);
                    p[2][0] = A2[0] * bflo(c2v.x); p[2][1] = A2[1] * bfhi(c2v.x);
                    p[2][2] = A2[2] * bflo(c2v.y); p[2][3] = A2[3] * bfhi(c2v.y);
                    bool cc = (len == 8 * pp + u + 2);   // t = 1 + 8*pp + u
#pragma unroll
                    for (int mt = 0; mt < 3; ++mt)
#pragma unroll
                        for (int r = 0; r < 4; ++r) dc[mt][r] = cc ? p[mt][r] : dc[mt][r];
                    lcap = cc ? logscale : lcap;
                    c0 = n0; c1 = n1; c2v = n2;
                    if (u == 7) {   // renorm once per chunk
                        float m = fmaxf(p[0][0], p[0][1]);
                        m = fmaxf(m, fmaxf(p[0][2], p[0][3]));
                        m = fmaxf(m, fmaxf(p[1][0], p[1][1]));
                        m = fmaxf(m, fmaxf(p[1][2], p[1][3]));
                        m = fmaxf(m, fmaxf(p[2][0], p[2][1]));
                        m = fmaxf(m, fmaxf(p[2][2], p[2][3]));
                        m = fmaxf(m, __shfl_xor(m, 16, 64));
                        m = fmaxf(m, __shfl_xor(m, 32, 64));
                        m = fmaxf(m, 1e-30f);
                        logscale += __logf(m);
                        float rm = __builtin_amdgcn_rcpf(m);
#pragma unroll
                        for (int mt = 0; mt < 3; ++mt)
#pragma unroll
                            for (int r = 0; r < 4; ++r) p[mt][r] *= rm;
                    }
                }
            }
            __builtin_amdgcn_s_barrier();
        }

        // epilogue
        float pe = 0.f;
#pragma unroll
        for (int mt = 0; mt < 3; ++mt) {
            int sb = mt * 16 + q * 4;
            pe = fmaf(dc[mt][0], __expf(end_tr[sb + 0]), pe);
            pe = fmaf(dc[mt][1], __expf(end_tr[sb + 1]), pe);
            pe = fmaf(dc[mt][2], __expf(end_tr[sb + 2]), pe);
            pe = fmaf(dc[mt][3], __expf(end_tr[sb + 3]), pe);
        }
        pe += __shfl_xor(pe, 16, 64);
        pe += __shfl_xor(pe, 32, 64);
        if (lane < 16) denomArr[bb] = lcap + __logf(pe);

    } else {
        // ================= PRODUCERS (waves 1..4, two teams) =================
        const int T = (wave - 1) >> 1;       // team parity: chunks c with (c&1)==T
        const int sub = (wave - 1) & 1;      // items i = sub*12 .. sub*12+11
        const int nb = lane & 15, q4 = lane >> 4;   // SAME mapping as consumer
        const int bb = wgbase + nb;
        const int len_v = lenArr[bb];
        int Lmax = len_v;
#pragma unroll
        for (int off = 1; off < 64; off <<= 1) {
            int o = __shfl_xor(Lmax, off, 64);
            Lmax = Lmax > o ? Lmax : o;
        }
        const int P = (Lmax + 6) >> 3;

        const float* emP = em + (size_t)bb * SS * TT + q4 * 4;
        float4 buf[12];   // single named buffer, constant indices -> registers

        for (int pp = -3; pp < P; ++pp) {
            int cv = pp + 1;                 // chunk to convert (loaded 2 periods ago)
            if (cv >= 0 && cv < P && (cv & 1) == T) {
                uint2* wp = &ring[(cv % NSLOT) * (CK * 3 * 64) + lane];
#pragma unroll
                for (int k = 0; k < 12; ++k) {
                    const int i = sub * 12 + k, u = i / 3, j = i % 3;
                    int t = 1 + 8 * cv + u;
                    bool live = t < len_v;
                    float4 v = buf[k];
                    unsigned ox = pk2bf(__expf(v.x), __expf(v.y));
                    unsigned oy = pk2bf(__expf(v.z), __expf(v.w));
                    uint2 o;
                    o.x = live ? ox : 0u;
                    o.y = live ? oy : 0u;
                    wp[u * 192 + j * 64] = o;
                }
            }
            int ci = pp + 3;                 // chunk to issue loads for (same parity)
            if (ci < P && (ci & 1) == T) {
#pragma unroll
                for (int k = 0; k < 12; ++k) {
                    const int i = sub * 12 + k, u = i / 3, j = i % 3;
                    int t = 1 + 8 * ci + u; t = t < SS ? t : SS - 1;
                    buf[k] = *(const float4*)(emP + (size_t)t * TT + j * 16);
                }
            }
            __builtin_amdgcn_s_waitcnt(0xC07F);  // lgkmcnt(0) only; vmcnt stays in flight
            __builtin_amdgcn_s_barrier();
        }
    }
}

__global__ __launch_bounds__(64)
void crf_reduce(const float* __restrict__ denom, const float* __restrict__ numer,
                float* __restrict__ out) {
    int lane = threadIdx.x;
    float s = 0.f;
    for (int i = lane; i < BB; i += 64) s += denom[i] - numer[i];
    s = wave_sum(s);
    if (lane == 0) out[0] = s * (1.0f / (float)BB);
}

extern "C" void kernel_launch(void* const* d_in, const int* in_sizes, int n_in,
                              void* d_out, int out_size, void* d_ws, size_t ws_size,
                              hipStream_t stream) {
    const float* emissions = (const float*)d_in[0];
    const int*   tags      = (const int*)d_in[1];
    const int*   mask      = (const int*)d_in[2];
    const float* start_tr  = (const float*)d_in[3];
    const float* end_tr    = (const float*)d_in[4];
    const float* trans     = (const float*)d_in[5];

    char* ws = (char*)d_ws;
    float* denom = (float*)ws;               // 512 f32
    float* numer = (float*)(ws + 2048);      // 512 f32
    int*   lenA  = (int*)(ws + 4096);        // 512 i32

    crf_numer<<<BB, 256, 0, stream>>>(emissions, tags, mask, start_tr, end_tr,
                                      trans, numer, lenA);
    crf_fwd<<<BB / GG, 320, 0, stream>>>(emissions, start_tr, end_tr, trans,
                                         lenA, denom);
    crf_reduce<<<1, 64, 0, stream>>>(denom, numer, (float*)d_out);
}